// Round 5
// baseline (190.908 us; speedup 1.0000x reference)
//
#include <hip/hip_runtime.h>
#include <math.h>

#define DEV static __device__ __forceinline__

DEV float rdlane(float v, int l) {
  return __int_as_float(__builtin_amdgcn_readlane(__float_as_int(v), l));
}

DEV float wave_sum64(float v) {
  v += __shfl_xor(v, 32, 64);
  v += __shfl_xor(v, 16, 64);
  v += __shfl_xor(v, 8, 64);
  v += __shfl_xor(v, 4, 64);
  v += __shfl_xor(v, 2, 64);
  v += __shfl_xor(v, 1, 64);
  return v;
}

// ---------------------------------------------------------------------------
// K_A: masked mean + stage 1 (nv = [en|acc] @ w_ent0 + b_ent0) for all items.
// One wave per group of 4 items; lane = output dim d.
// LDS: Lrel[65][64] + LweT[64][132] = 12608 fl = 49.25 KB -> 3 blocks/CU,
// 24 waves/CU. en rows via SMEM (uniform float4); acc via readlane.
// Outputs: ws_nv[item][128] (nv0|nv1), ws_idx[item] = rsel.
// ---------------------------------------------------------------------------
__global__ __launch_bounds__(512, 6)
void k_mean_s1(const int* __restrict__ relations, const int* __restrict__ entity_pairs,
               const int* __restrict__ train_edges,
               const int* __restrict__ entity2edges, const int* __restrict__ edge2entities,
               const int* __restrict__ edge2relation,
               const float* __restrict__ ent_emb, const float* __restrict__ rel_emb,
               const float* __restrict__ w_ent0, const float* __restrict__ b_ent0,
               float* __restrict__ ws_nv, int* __restrict__ ws_idx, int n_items)
{
  extern __shared__ float L[];
  float* Lrel = L;             // [65][64], row 64 = zeros
  float* LweT = L + 4160;      // [64][132]: LweT[d*132+i] = w_ent0[i][d]
  for (int t = threadIdx.x; t < 4096; t += 512) Lrel[t] = rel_emb[t];
  if (threadIdx.x < 64) Lrel[4096 + threadIdx.x] = 0.f;
  for (int t = threadIdx.x; t < 8192; t += 512)
    LweT[(t & 63) * 132 + (t >> 6)] = w_ent0[t];
  __syncthreads();

  const int lane = threadIdx.x & 63;
  const int wid = threadIdx.x >> 6;
  const int ngroups = (n_items + 3) >> 2;
  const int g = blockIdx.x * 8 + wid;
  if (g >= ngroups) return;

  const float bent = b_ent0[lane];
  const float* wrow = &LweT[lane * 132];

  int te[4], rsel[4], n0s[4], n1s[4], itm[4];
#pragma unroll
  for (int q = 0; q < 4; ++q) {
    int item = g * 4 + q;
    if (item >= n_items) item = n_items - 1;  // benign duplicate
    itm[q] = item;
    const int b = item / 33;
    const int j = item - b * 33;
    te[q] = __builtin_amdgcn_readfirstlane(train_edges[b]);
    int n0, n1, rs;
    if (j < 32) {  // wave-uniform branch
      const int eself = entity2edges[entity_pairs[b * 2 + (j >> 4)] * 16 + (j & 15)];
      rs = edge2relation[eself];
      n0 = edge2entities[eself * 2 + 0];
      n1 = edge2entities[eself * 2 + 1];
    } else {
      rs = relations[b];
      n0 = entity_pairs[b * 2 + 0];
      n1 = entity_pairs[b * 2 + 1];
    }
    rsel[q] = __builtin_amdgcn_readfirstlane(rs);
    n0s[q] = __builtin_amdgcn_readfirstlane(n0);
    n1s[q] = __builtin_amdgcn_readfirstlane(n1);
  }

  // --- masked mean over 2x16 neighbor relation rows ---
  float acc0[4], acc1[4];
#pragma unroll
  for (int q = 0; q < 4; ++q) {
    const int myent = ((lane >> 4) & 1) ? n1s[q] : n0s[q];
    const int e = entity2edges[myent * 16 + (lane & 15)];
    const bool keep = (e != te[q]);
    const unsigned long long bal = __ballot(keep);
    const int r = keep ? edge2relation[e] : 64;  // row 64 of Lrel is zeros
    float a0 = 0.f, a1 = 0.f;
#pragma unroll
    for (int s = 0; s < 16; ++s) {
      const int rA = __builtin_amdgcn_readlane(r, s);
      const int rB = __builtin_amdgcn_readlane(r, s + 16);
      a0 += Lrel[rA * 64 + lane];
      a1 += Lrel[rB * 64 + lane];
    }
    const int c0 = __popcll(bal & 0xFFFFull);
    const int c1 = __popcll(bal & 0xFFFF0000ull);
    acc0[q] = a0 / (float)(c0 ? c0 : 1);
    acc1[q] = a1 / (float)(c1 ? c1 : 1);
  }

  // --- stage 1: nv_c = [en_c | acc_c] @ w_ent0 + b_ent0 ---
  float nv0[4], nv1[4];
#pragma unroll
  for (int q = 0; q < 4; ++q) { nv0[q] = bent; nv1[q] = bent; }
#pragma unroll
  for (int ib = 0; ib < 16; ++ib) {
    const float4 wE = *(const float4*)&wrow[4 * ib];
    const float4 wA = *(const float4*)&wrow[64 + 4 * ib];
#pragma unroll
    for (int q = 0; q < 4; ++q) {
      const float4 xa = *(const float4*)(ent_emb + (size_t)n0s[q] * 64 + 4 * ib);
      const float4 xb = *(const float4*)(ent_emb + (size_t)n1s[q] * 64 + 4 * ib);
      nv0[q] = fmaf(xa.x, wE.x, nv0[q]); nv0[q] = fmaf(xa.y, wE.y, nv0[q]);
      nv0[q] = fmaf(xa.z, wE.z, nv0[q]); nv0[q] = fmaf(xa.w, wE.w, nv0[q]);
      nv1[q] = fmaf(xb.x, wE.x, nv1[q]); nv1[q] = fmaf(xb.y, wE.y, nv1[q]);
      nv1[q] = fmaf(xb.z, wE.z, nv1[q]); nv1[q] = fmaf(xb.w, wE.w, nv1[q]);
      nv0[q] = fmaf(rdlane(acc0[q], 4 * ib + 0), wA.x, nv0[q]);
      nv0[q] = fmaf(rdlane(acc0[q], 4 * ib + 1), wA.y, nv0[q]);
      nv0[q] = fmaf(rdlane(acc0[q], 4 * ib + 2), wA.z, nv0[q]);
      nv0[q] = fmaf(rdlane(acc0[q], 4 * ib + 3), wA.w, nv0[q]);
      nv1[q] = fmaf(rdlane(acc1[q], 4 * ib + 0), wA.x, nv1[q]);
      nv1[q] = fmaf(rdlane(acc1[q], 4 * ib + 1), wA.y, nv1[q]);
      nv1[q] = fmaf(rdlane(acc1[q], 4 * ib + 2), wA.z, nv1[q]);
      nv1[q] = fmaf(rdlane(acc1[q], 4 * ib + 3), wA.w, nv1[q]);
    }
  }
#pragma unroll
  for (int q = 0; q < 4; ++q) {
    ws_nv[(size_t)itm[q] * 128 + lane] = nv0[q];
    ws_nv[(size_t)itm[q] * 128 + 64 + lane] = nv1[q];
    if (lane == 0) ws_idx[itm[q]] = rsel[q];
  }
}

// ---------------------------------------------------------------------------
// K_B: stage 2: sv = [self | nv0 | nv1] @ w0 + b0.
// All x-operands memory-resident -> uniform SMEM float4 reads, zero readlanes.
// LDS: Lw0T[64][196] = 49 KB -> 3 blocks/CU, 24 waves/CU.
// ---------------------------------------------------------------------------
__global__ __launch_bounds__(512, 6)
void k_s2(const float* __restrict__ rel_emb,
          const float* __restrict__ w0, const float* __restrict__ b0,
          const float* __restrict__ ws_nv, const int* __restrict__ ws_idx,
          float* __restrict__ v1ws, int n_items)
{
  extern __shared__ float L[];
  float* Lw0T = L;             // [64][196]: Lw0T[d*196+i] = w0[i][d]
  for (int t = threadIdx.x; t < 12288; t += 512)
    Lw0T[(t & 63) * 196 + (t >> 6)] = w0[t];
  __syncthreads();

  const int lane = threadIdx.x & 63;
  const int wid = threadIdx.x >> 6;
  const int ngroups = (n_items + 3) >> 2;
  const int g = blockIdx.x * 8 + wid;
  if (g >= ngroups) return;

  const float* w0row = &Lw0T[lane * 196];
  int itm[4], rsel[4];
#pragma unroll
  for (int q = 0; q < 4; ++q) {
    int item = g * 4 + q;
    if (item >= n_items) item = n_items - 1;
    itm[q] = item;
    rsel[q] = __builtin_amdgcn_readfirstlane(ws_idx[item]);
  }

  float sv[4];
#pragma unroll
  for (int q = 0; q < 4; ++q) sv[q] = b0[lane];
#pragma unroll
  for (int ib = 0; ib < 16; ++ib) {
    const float4 wS = *(const float4*)&w0row[4 * ib];
    const float4 wN0 = *(const float4*)&w0row[64 + 4 * ib];
    const float4 wN1 = *(const float4*)&w0row[128 + 4 * ib];
#pragma unroll
    for (int q = 0; q < 4; ++q) {
      const float4 xs = *(const float4*)(rel_emb + (size_t)rsel[q] * 64 + 4 * ib);
      const float4 x0 = *(const float4*)(ws_nv + (size_t)itm[q] * 128 + 4 * ib);
      const float4 x1 = *(const float4*)(ws_nv + (size_t)itm[q] * 128 + 64 + 4 * ib);
      sv[q] = fmaf(xs.x, wS.x, sv[q]); sv[q] = fmaf(xs.y, wS.y, sv[q]);
      sv[q] = fmaf(xs.z, wS.z, sv[q]); sv[q] = fmaf(xs.w, wS.w, sv[q]);
      sv[q] = fmaf(x0.x, wN0.x, sv[q]); sv[q] = fmaf(x0.y, wN0.y, sv[q]);
      sv[q] = fmaf(x0.z, wN0.z, sv[q]); sv[q] = fmaf(x0.w, wN0.w, sv[q]);
      sv[q] = fmaf(x1.x, wN1.x, sv[q]); sv[q] = fmaf(x1.y, wN1.y, sv[q]);
      sv[q] = fmaf(x1.z, wN1.z, sv[q]); sv[q] = fmaf(x1.w, wN1.w, sv[q]);
    }
  }
#pragma unroll
  for (int q = 0; q < 4; ++q) v1ws[(size_t)itm[q] * 64 + lane] = sv[q];
}

// ---------------------------------------------------------------------------
// K2: hop-2 aggregation + attention + score. One wave per b.
// Regridded: 256 blocks x 256 thr (4 b/block) so ALL CUs have work.
// LDS: LweT1 + Lw1T + L{q,k,v}T = 34048 fl = 133 KB.
// ---------------------------------------------------------------------------
__global__ __launch_bounds__(256, 2)
void k_ctx_score(const int* __restrict__ entity_pairs, const int* __restrict__ train_edges,
                 const int* __restrict__ user_ids, const int* __restrict__ top_k_ids,
                 const int* __restrict__ entity2edges,
                 const float* __restrict__ ent_emb, const float* __restrict__ user_emb,
                 const float* __restrict__ w_ent1, const float* __restrict__ b_ent1,
                 const float* __restrict__ w1, const float* __restrict__ b1,
                 const float* __restrict__ wq, const float* __restrict__ bq,
                 const float* __restrict__ wk, const float* __restrict__ bk,
                 const float* __restrict__ wv, const float* __restrict__ bv,
                 const float* __restrict__ w_s, const float* __restrict__ b_s,
                 const float* __restrict__ v1ws, float* __restrict__ out, int bs)
{
  extern __shared__ float Lw[];
  float* LweT = Lw;            // [64][132]
  float* Lw1T = Lw + 8448;     // [64][196]
  float* LqT  = Lw + 20992;    // [64][68]
  float* LkT  = Lw + 25344;    // [64][68]
  float* LvT  = Lw + 29696;    // [64][68]
  for (int t = threadIdx.x; t < 8192; t += 256)
    LweT[(t & 63) * 132 + (t >> 6)] = w_ent1[t];
  for (int t = threadIdx.x; t < 12288; t += 256)
    Lw1T[(t & 63) * 196 + (t >> 6)] = w1[t];
  for (int t = threadIdx.x; t < 4096; t += 256) {
    const int d = t & 63, i = t >> 6;
    LqT[d * 68 + i] = wq[t];
    LkT[d * 68 + i] = wk[t];
    LvT[d * 68 + i] = wv[t];
  }
  __syncthreads();

  const int lane = threadIdx.x & 63;
  const int wid = threadIdx.x >> 6;
  const int b = blockIdx.x * 4 + wid;
  if (b >= bs) return;

  const int te = __builtin_amdgcn_readfirstlane(train_edges[b]);
  const int n0 = __builtin_amdgcn_readfirstlane(entity_pairs[b * 2 + 0]);
  const int n1 = __builtin_amdgcn_readfirstlane(entity_pairs[b * 2 + 1]);
  const int uid = __builtin_amdgcn_readfirstlane(user_ids[b]);
  int tkid[10];
#pragma unroll
  for (int k = 0; k < 10; ++k)
    tkid[k] = __builtin_amdgcn_readfirstlane(top_k_ids[b * 10 + k]);

  const int myent = ((lane >> 4) & 1) ? n1 : n0;
  const int e = entity2edges[myent * 16 + (lane & 15)];
  const unsigned long long bal = __ballot(e != te);
  const int cnt0 = __popcll(bal & 0xFFFFull);
  const int cnt1 = __popcll(bal & 0xFFFF0000ull);

  const float* vbase = v1ws + (size_t)b * 33 * 64;
  float acc0 = 0.f, acc1 = 0.f;
#pragma unroll
  for (int s = 0; s < 16; ++s) {
    const float mA = (float)((bal >> s) & 1ull);
    const float mB = (float)((bal >> (s + 16)) & 1ull);
    acc0 = fmaf(mA, vbase[s * 64 + lane], acc0);
    acc1 = fmaf(mB, vbase[(16 + s) * 64 + lane], acc1);
  }
  acc0 *= 1.0f / (float)(cnt0 ? cnt0 : 1);
  acc1 *= 1.0f / (float)(cnt1 ? cnt1 : 1);

  // --- nv = [en | acc] @ w_ent1 + b_ent1 ---
  float nv0 = b_ent1[lane], nv1 = nv0;
  const float* wrow = &LweT[lane * 132];
#pragma unroll
  for (int ib = 0; ib < 16; ++ib) {
    const float4 wE = *(const float4*)&wrow[4 * ib];
    const float4 wA = *(const float4*)&wrow[64 + 4 * ib];
    const float4 xa = *(const float4*)(ent_emb + (size_t)n0 * 64 + 4 * ib);
    const float4 xb = *(const float4*)(ent_emb + (size_t)n1 * 64 + 4 * ib);
    nv0 = fmaf(xa.x, wE.x, nv0); nv0 = fmaf(xa.y, wE.y, nv0);
    nv0 = fmaf(xa.z, wE.z, nv0); nv0 = fmaf(xa.w, wE.w, nv0);
    nv1 = fmaf(xb.x, wE.x, nv1); nv1 = fmaf(xb.y, wE.y, nv1);
    nv1 = fmaf(xb.z, wE.z, nv1); nv1 = fmaf(xb.w, wE.w, nv1);
    nv0 = fmaf(rdlane(acc0, 4 * ib + 0), wA.x, nv0);
    nv0 = fmaf(rdlane(acc0, 4 * ib + 1), wA.y, nv0);
    nv0 = fmaf(rdlane(acc0, 4 * ib + 2), wA.z, nv0);
    nv0 = fmaf(rdlane(acc0, 4 * ib + 3), wA.w, nv0);
    nv1 = fmaf(rdlane(acc1, 4 * ib + 0), wA.x, nv1);
    nv1 = fmaf(rdlane(acc1, 4 * ib + 1), wA.y, nv1);
    nv1 = fmaf(rdlane(acc1, 4 * ib + 2), wA.z, nv1);
    nv1 = fmaf(rdlane(acc1, 4 * ib + 3), wA.w, nv1);
  }

  // --- ctx = [self | nv0 | nv1] @ w1 + b1 ---
  float ctx = b1[lane];
  const float* w1row = &Lw1T[lane * 196];
  const float* selfp = vbase + 32 * 64;
#pragma unroll
  for (int ib = 0; ib < 16; ++ib) {
    const float4 wS = *(const float4*)&w1row[4 * ib];
    const float4 wN0 = *(const float4*)&w1row[64 + 4 * ib];
    const float4 wN1 = *(const float4*)&w1row[128 + 4 * ib];
    const float4 xs = *(const float4*)(selfp + 4 * ib);
    ctx = fmaf(xs.x, wS.x, ctx); ctx = fmaf(xs.y, wS.y, ctx);
    ctx = fmaf(xs.z, wS.z, ctx); ctx = fmaf(xs.w, wS.w, ctx);
    ctx = fmaf(rdlane(nv0, 4 * ib + 0), wN0.x, ctx);
    ctx = fmaf(rdlane(nv0, 4 * ib + 1), wN0.y, ctx);
    ctx = fmaf(rdlane(nv0, 4 * ib + 2), wN0.z, ctx);
    ctx = fmaf(rdlane(nv0, 4 * ib + 3), wN0.w, ctx);
    ctx = fmaf(rdlane(nv1, 4 * ib + 0), wN1.x, ctx);
    ctx = fmaf(rdlane(nv1, 4 * ib + 1), wN1.y, ctx);
    ctx = fmaf(rdlane(nv1, 4 * ib + 2), wN1.z, ctx);
    ctx = fmaf(rdlane(nv1, 4 * ib + 3), wN1.w, ctx);
  }

  // --- q = u @ wq + bq ---
  float q = bq[lane];
  const float* qrow = &LqT[lane * 68];
#pragma unroll
  for (int ib = 0; ib < 16; ++ib) {
    const float4 wQ = *(const float4*)&qrow[4 * ib];
    const float4 xu = *(const float4*)(user_emb + (size_t)uid * 64 + 4 * ib);
    q = fmaf(xu.x, wQ.x, q); q = fmaf(xu.y, wQ.y, q);
    q = fmaf(xu.z, wQ.z, q); q = fmaf(xu.w, wQ.w, q);
  }

  // --- K/V for 10 candidates ---
  float kk[10], vv[10];
  const float bkv = bk[lane], bvv = bv[lane];
#pragma unroll
  for (int k = 0; k < 10; ++k) { kk[k] = bkv; vv[k] = bvv; }
  const float* krow = &LkT[lane * 68];
  const float* vrow = &LvT[lane * 68];
#pragma unroll
  for (int ib = 0; ib < 16; ++ib) {
    const float4 wK = *(const float4*)&krow[4 * ib];
    const float4 wV = *(const float4*)&vrow[4 * ib];
#pragma unroll
    for (int k = 0; k < 10; ++k) {
      const float4 xt = *(const float4*)(ent_emb + (size_t)tkid[k] * 64 + 4 * ib);
      kk[k] = fmaf(xt.x, wK.x, kk[k]); kk[k] = fmaf(xt.y, wK.y, kk[k]);
      kk[k] = fmaf(xt.z, wK.z, kk[k]); kk[k] = fmaf(xt.w, wK.w, kk[k]);
      vv[k] = fmaf(xt.x, wV.x, vv[k]); vv[k] = fmaf(xt.y, wV.y, vv[k]);
      vv[k] = fmaf(xt.z, wV.z, vv[k]); vv[k] = fmaf(xt.w, wV.w, vv[k]);
    }
  }

  float lg[10];
#pragma unroll
  for (int k = 0; k < 10; ++k) lg[k] = wave_sum64(q * kk[k]) * 0.125f;  // 1/sqrt(64)
  float m = lg[0];
#pragma unroll
  for (int k = 1; k < 10; ++k) m = fmaxf(m, lg[k]);
  float den = 0.f;
  float att[10];
#pragma unroll
  for (int k = 0; k < 10; ++k) { att[k] = expf(lg[k] - m); den += att[k]; }
  const float invden = 1.0f / den;
  float uatt = 0.f;
#pragma unroll
  for (int k = 0; k < 10; ++k) uatt = fmaf(att[k] * invden, vv[k], uatt);

  const float sc = wave_sum64(uatt * ctx + ctx * w_s[lane]);
  if (lane == 0) out[b] = sc + b_s[0];
}

extern "C" void kernel_launch(void* const* d_in, const int* in_sizes, int n_in,
                              void* d_out, int out_size, void* d_ws, size_t ws_size,
                              hipStream_t stream) {
  const int* relations     = (const int*)d_in[0];
  const int* entity_pairs  = (const int*)d_in[1];
  const int* train_edges   = (const int*)d_in[2];
  const int* user_ids      = (const int*)d_in[3];
  const int* top_k_ids     = (const int*)d_in[4];
  const int* entity2edges  = (const int*)d_in[5];
  const int* edge2entities = (const int*)d_in[6];
  const int* edge2relation = (const int*)d_in[7];
  const float* ent_emb  = (const float*)d_in[8];
  const float* rel_emb  = (const float*)d_in[9];
  const float* user_emb = (const float*)d_in[10];
  const float* w_ent0 = (const float*)d_in[11];
  const float* b_ent0 = (const float*)d_in[12];
  const float* w0     = (const float*)d_in[13];
  const float* b0     = (const float*)d_in[14];
  const float* w_ent1 = (const float*)d_in[15];
  const float* b_ent1 = (const float*)d_in[16];
  const float* w1     = (const float*)d_in[17];
  const float* b1     = (const float*)d_in[18];
  const float* wq  = (const float*)d_in[19];
  const float* bq  = (const float*)d_in[20];
  const float* wk  = (const float*)d_in[21];
  const float* bk  = (const float*)d_in[22];
  const float* wv  = (const float*)d_in[23];
  const float* bv  = (const float*)d_in[24];
  const float* w_s = (const float*)d_in[25];
  const float* b_s = (const float*)d_in[26];

  const int bs = in_sizes[0];
  const int n_items = bs * 33;
  const int ngroups = (n_items + 3) >> 2;
  const int nblkAB = (ngroups + 7) >> 3;

  // Workspace layout: nv[n_items*128] | v1[n_items*64] | idx[n_items]
  float* ws_nv = (float*)d_ws;
  float* v1ws = ws_nv + (size_t)n_items * 128;
  int* ws_idx = (int*)(v1ws + (size_t)n_items * 64);

  k_mean_s1<<<dim3(nblkAB), dim3(512), 12608 * sizeof(float), stream>>>(
      relations, entity_pairs, train_edges, entity2edges, edge2entities,
      edge2relation, ent_emb, rel_emb, w_ent0, b_ent0, ws_nv, ws_idx, n_items);

  k_s2<<<dim3(nblkAB), dim3(512), 12544 * sizeof(float), stream>>>(
      rel_emb, w0, b0, ws_nv, ws_idx, v1ws, n_items);

  k_ctx_score<<<dim3((bs + 3) / 4), dim3(256), 34048 * sizeof(float), stream>>>(
      entity_pairs, train_edges, user_ids, top_k_ids, entity2edges,
      ent_emb, user_emb, w_ent1, b_ent1, w1, b1, wq, bq, wk, bk, wv, bv,
      w_s, b_s, v1ws, (float*)d_out, bs);
}

// Round 6
// 77.248 us; speedup vs baseline: 2.4714x; 2.4714x over previous
//
#include <hip/hip_runtime.h>
#include <hip/hip_bf16.h>
#include <hip/hip_fp16.h>
#include <math.h>

#define DEV static __device__ __forceinline__

typedef float f32x4 __attribute__((ext_vector_type(4)));
typedef _Float16 f16x8 __attribute__((ext_vector_type(8)));

DEV _Float16 f2h(float x) { return (_Float16)x; }

DEV float rdlane(float v, int l) {
  return __int_as_float(__builtin_amdgcn_readlane(__float_as_int(v), l));
}

DEV float wave_sum64(float v) {
  v += __shfl_xor(v, 32, 64);
  v += __shfl_xor(v, 16, 64);
  v += __shfl_xor(v, 8, 64);
  v += __shfl_xor(v, 4, 64);
  v += __shfl_xor(v, 2, 64);
  v += __shfl_xor(v, 1, 64);
  return v;
}

// ---------------------------------------------------------------------------
// k_pack: per item compute masked-mean acc0/acc1 and emit fp16 GEMM-A rows:
//   X1[2*item+c] = [en_c (64) | acc_c (64)]  (fp16, 128 elems = 256B rows)
// plus rsel[item]. One wave per 4 items; lane = dim. No LDS; rel_emb via L1.
// ---------------------------------------------------------------------------
__global__ __launch_bounds__(512)
void k_pack(const int* __restrict__ relations, const int* __restrict__ entity_pairs,
            const int* __restrict__ train_edges,
            const int* __restrict__ entity2edges, const int* __restrict__ edge2entities,
            const int* __restrict__ edge2relation,
            const float* __restrict__ ent_emb, const float* __restrict__ rel_emb,
            _Float16* __restrict__ X1, int* __restrict__ rsel_arr, int n_items)
{
  const int lane = threadIdx.x & 63;
  const int wid = threadIdx.x >> 6;
  const int g = blockIdx.x * 8 + wid;
  if (g * 4 >= n_items) return;

#pragma unroll
  for (int q = 0; q < 4; ++q) {
    int item = g * 4 + q;
    if (item >= n_items) item = n_items - 1;  // benign duplicate
    const int b = item / 33;
    const int j = item - b * 33;
    const int te = __builtin_amdgcn_readfirstlane(train_edges[b]);
    int n0, n1, rs;
    if (j < 32) {  // wave-uniform branch
      const int eself = entity2edges[entity_pairs[b * 2 + (j >> 4)] * 16 + (j & 15)];
      rs = edge2relation[eself];
      n0 = edge2entities[eself * 2 + 0];
      n1 = edge2entities[eself * 2 + 1];
    } else {
      rs = relations[b];
      n0 = entity_pairs[b * 2 + 0];
      n1 = entity_pairs[b * 2 + 1];
    }
    rs = __builtin_amdgcn_readfirstlane(rs);
    n0 = __builtin_amdgcn_readfirstlane(n0);
    n1 = __builtin_amdgcn_readfirstlane(n1);

    // masked mean over 2x16 neighbor relation rows (rel_emb is 16KB -> L1)
    const int myent = ((lane >> 4) & 1) ? n1 : n0;
    const int e = entity2edges[myent * 16 + (lane & 15)];
    const bool keep = (e != te);
    const unsigned long long bal = __ballot(keep);
    const int r = edge2relation[e];
    float a0 = 0.f, a1 = 0.f;
#pragma unroll
    for (int s = 0; s < 16; ++s) {
      const int rA = __builtin_amdgcn_readlane(r, s);
      const int rB = __builtin_amdgcn_readlane(r, s + 16);
      const float mA = (float)((bal >> s) & 1ull);
      const float mB = (float)((bal >> (s + 16)) & 1ull);
      a0 = fmaf(mA, rel_emb[rA * 64 + lane], a0);
      a1 = fmaf(mB, rel_emb[rB * 64 + lane], a1);
    }
    const int c0 = __popcll(bal & 0xFFFFull);
    const int c1 = __popcll(bal & 0xFFFF0000ull);
    a0 *= 1.0f / (float)(c0 ? c0 : 1);
    a1 *= 1.0f / (float)(c1 ? c1 : 1);

    const float en0 = ent_emb[(size_t)n0 * 64 + lane];
    const float en1 = ent_emb[(size_t)n1 * 64 + lane];
    _Float16* rowp = X1 + (size_t)item * 256;
    rowp[lane] = f2h(en0);
    rowp[64 + lane] = f2h(a0);
    rowp[128 + lane] = f2h(en1);
    rowp[192 + lane] = f2h(a1);
    if (lane == 0) rsel_arr[item] = rs;
  }
}

// ---------------------------------------------------------------------------
// k_gemm1: nv = X1[67584][128] @ w_ent0[128][64] + b_ent0, MFMA 16x16x32 f16.
// 32 rows/wave, 4 waves/block. B pre-permuted to fragment layout in LDS (16KB).
// Output row rr=2i+c -> nv[i*128 + c*64 + n] (fp16).
// Fragment convention: A[m = l&15][k = kc*32 + (l>>4)*8 + j],
//                      B[k = kc*32 + (l>>4)*8 + j][n = l&15],
//                      D[m = (l>>4)*4 + r][n = l&15].
// ---------------------------------------------------------------------------
__global__ __launch_bounds__(256)
void k_gemm1(const _Float16* __restrict__ X1, const float* __restrict__ w,
             const float* __restrict__ bias, _Float16* __restrict__ nv, int nrows)
{
  __shared__ _Float16 Bl[4 * 4 * 64 * 8];  // [kc][nt][lane][8]
  for (int t = threadIdx.x; t < 8192; t += 256) {
    const int k = t >> 6, n = t & 63;
    const int kc = k >> 5, lg = (k >> 3) & 3, jj = k & 7;
    const int nt = n >> 4, ln = lg * 16 + (n & 15);
    Bl[((kc * 4 + nt) * 64 + ln) * 8 + jj] = f2h(w[t]);
  }
  __syncthreads();

  const int lane = threadIdx.x & 63;
  const int wid = threadIdx.x >> 6;
  const int row0 = (blockIdx.x * 4 + wid) * 32;
  if (row0 >= nrows) return;
  const int l15 = lane & 15, lg = lane >> 4;

  float bs[4];
#pragma unroll
  for (int nt = 0; nt < 4; ++nt) bs[nt] = bias[nt * 16 + l15];

  f32x4 acc0[4], acc1[4];
#pragma unroll
  for (int nt = 0; nt < 4; ++nt) {
    acc0[nt] = (f32x4)(0.f);
    acc1[nt] = (f32x4)(0.f);
  }

  const _Float16* a0p = X1 + (size_t)(row0 + l15) * 128 + lg * 8;
  const _Float16* a1p = a0p + 16 * 128;
#pragma unroll
  for (int kc = 0; kc < 4; ++kc) {
    const f16x8 A0 = *(const f16x8*)(a0p + kc * 32);
    const f16x8 A1 = *(const f16x8*)(a1p + kc * 32);
#pragma unroll
    for (int nt = 0; nt < 4; ++nt) {
      const f16x8 B = *(const f16x8*)&Bl[((kc * 4 + nt) * 64 + lane) * 8];
      acc0[nt] = __builtin_amdgcn_mfma_f32_16x16x32_f16(A0, B, acc0[nt], 0, 0, 0);
      acc1[nt] = __builtin_amdgcn_mfma_f32_16x16x32_f16(A1, B, acc1[nt], 0, 0, 0);
    }
  }

#pragma unroll
  for (int mt = 0; mt < 2; ++mt) {
#pragma unroll
    for (int nt = 0; nt < 4; ++nt) {
#pragma unroll
      for (int r = 0; r < 4; ++r) {
        const int row = row0 + mt * 16 + lg * 4 + r;
        const float v = (mt ? acc1[nt][r] : acc0[nt][r]) + bs[nt];
        nv[(size_t)(row >> 1) * 128 + (row & 1) * 64 + nt * 16 + l15] = f2h(v);
      }
    }
  }
}

// ---------------------------------------------------------------------------
// k_gemm2: v1 = [self | nv0 | nv1][33792][192] @ w0[192][64] + b0 (fp32 out).
// self rows from an 8KB fp16 rel-table in LDS (indexed by rsel); nv from ws.
// 16 rows/wave, 4 waves/block. B in LDS (24KB).
// ---------------------------------------------------------------------------
__global__ __launch_bounds__(256)
void k_gemm2(const _Float16* __restrict__ nv, const int* __restrict__ rsel_arr,
             const float* __restrict__ rel_emb, const float* __restrict__ w,
             const float* __restrict__ bias, float* __restrict__ v1, int nrows)
{
  __shared__ _Float16 Bl[6 * 4 * 64 * 8];  // 24KB
  __shared__ _Float16 Lrel[64 * 64];       // 8KB fp16 rel table
  for (int t = threadIdx.x; t < 12288; t += 256) {
    const int k = t >> 6, n = t & 63;
    const int kc = k >> 5, lg = (k >> 3) & 3, jj = k & 7;
    const int nt = n >> 4, ln = lg * 16 + (n & 15);
    Bl[((kc * 4 + nt) * 64 + ln) * 8 + jj] = f2h(w[t]);
  }
  for (int t = threadIdx.x; t < 4096; t += 256) Lrel[t] = f2h(rel_emb[t]);
  __syncthreads();

  const int lane = threadIdx.x & 63;
  const int wid = threadIdx.x >> 6;
  const int row0 = (blockIdx.x * 4 + wid) * 16;
  if (row0 >= nrows) return;
  const int l15 = lane & 15, lg = lane >> 4;

  const int rs = rsel_arr[row0 + l15];
  float bs[4];
#pragma unroll
  for (int nt = 0; nt < 4; ++nt) bs[nt] = bias[nt * 16 + l15];

  f32x4 acc[4];
#pragma unroll
  for (int nt = 0; nt < 4; ++nt) acc[nt] = (f32x4)(0.f);

  const _Float16* anv = nv + (size_t)(row0 + l15) * 128 + lg * 8;
#pragma unroll
  for (int kc = 0; kc < 6; ++kc) {
    f16x8 A;
    if (kc < 2) A = *(const f16x8*)&Lrel[rs * 64 + kc * 32 + lg * 8];
    else A = *(const f16x8*)(anv + (kc - 2) * 32);
#pragma unroll
    for (int nt = 0; nt < 4; ++nt) {
      const f16x8 B = *(const f16x8*)&Bl[((kc * 4 + nt) * 64 + lane) * 8];
      acc[nt] = __builtin_amdgcn_mfma_f32_16x16x32_f16(A, B, acc[nt], 0, 0, 0);
    }
  }

#pragma unroll
  for (int nt = 0; nt < 4; ++nt) {
#pragma unroll
    for (int r = 0; r < 4; ++r) {
      const int row = row0 + lg * 4 + r;
      v1[(size_t)row * 64 + nt * 16 + l15] = acc[nt][r] + bs[nt];
    }
  }
}

// ---------------------------------------------------------------------------
// K2: hop-2 aggregation + attention + score (fp32). One wave per b.
// 256 blocks x 256 thr. LDS: LweT1 + Lw1T + L{q,k,v}T = 34048 fl = 133 KB.
// ---------------------------------------------------------------------------
__global__ __launch_bounds__(256, 2)
void k_ctx_score(const int* __restrict__ entity_pairs, const int* __restrict__ train_edges,
                 const int* __restrict__ user_ids, const int* __restrict__ top_k_ids,
                 const int* __restrict__ entity2edges,
                 const float* __restrict__ ent_emb, const float* __restrict__ user_emb,
                 const float* __restrict__ w_ent1, const float* __restrict__ b_ent1,
                 const float* __restrict__ w1, const float* __restrict__ b1,
                 const float* __restrict__ wq, const float* __restrict__ bq,
                 const float* __restrict__ wk, const float* __restrict__ bk,
                 const float* __restrict__ wv, const float* __restrict__ bv,
                 const float* __restrict__ w_s, const float* __restrict__ b_s,
                 const float* __restrict__ v1ws, float* __restrict__ out, int bs)
{
  extern __shared__ float Lw[];
  float* LweT = Lw;            // [64][132]
  float* Lw1T = Lw + 8448;     // [64][196]
  float* LqT  = Lw + 20992;    // [64][68]
  float* LkT  = Lw + 25344;    // [64][68]
  float* LvT  = Lw + 29696;    // [64][68]
  for (int t = threadIdx.x; t < 8192; t += 256)
    LweT[(t & 63) * 132 + (t >> 6)] = w_ent1[t];
  for (int t = threadIdx.x; t < 12288; t += 256)
    Lw1T[(t & 63) * 196 + (t >> 6)] = w1[t];
  for (int t = threadIdx.x; t < 4096; t += 256) {
    const int d = t & 63, i = t >> 6;
    LqT[d * 68 + i] = wq[t];
    LkT[d * 68 + i] = wk[t];
    LvT[d * 68 + i] = wv[t];
  }
  __syncthreads();

  const int lane = threadIdx.x & 63;
  const int wid = threadIdx.x >> 6;
  const int b = blockIdx.x * 4 + wid;
  if (b >= bs) return;

  const int te = __builtin_amdgcn_readfirstlane(train_edges[b]);
  const int n0 = __builtin_amdgcn_readfirstlane(entity_pairs[b * 2 + 0]);
  const int n1 = __builtin_amdgcn_readfirstlane(entity_pairs[b * 2 + 1]);
  const int uid = __builtin_amdgcn_readfirstlane(user_ids[b]);
  int tkid[10];
#pragma unroll
  for (int k = 0; k < 10; ++k)
    tkid[k] = __builtin_amdgcn_readfirstlane(top_k_ids[b * 10 + k]);

  const int myent = ((lane >> 4) & 1) ? n1 : n0;
  const int e = entity2edges[myent * 16 + (lane & 15)];
  const unsigned long long bal = __ballot(e != te);
  const int cnt0 = __popcll(bal & 0xFFFFull);
  const int cnt1 = __popcll(bal & 0xFFFF0000ull);

  const float* vbase = v1ws + (size_t)b * 33 * 64;
  float acc0 = 0.f, acc1 = 0.f;
#pragma unroll
  for (int s = 0; s < 16; ++s) {
    const float mA = (float)((bal >> s) & 1ull);
    const float mB = (float)((bal >> (s + 16)) & 1ull);
    acc0 = fmaf(mA, vbase[s * 64 + lane], acc0);
    acc1 = fmaf(mB, vbase[(16 + s) * 64 + lane], acc1);
  }
  acc0 *= 1.0f / (float)(cnt0 ? cnt0 : 1);
  acc1 *= 1.0f / (float)(cnt1 ? cnt1 : 1);

  // --- nv = [en | acc] @ w_ent1 + b_ent1 ---
  float nv0 = b_ent1[lane], nv1 = nv0;
  const float* wrow = &LweT[lane * 132];
#pragma unroll
  for (int ib = 0; ib < 16; ++ib) {
    const float4 wE = *(const float4*)&wrow[4 * ib];
    const float4 wA = *(const float4*)&wrow[64 + 4 * ib];
    const float4 xa = *(const float4*)(ent_emb + (size_t)n0 * 64 + 4 * ib);
    const float4 xb = *(const float4*)(ent_emb + (size_t)n1 * 64 + 4 * ib);
    nv0 = fmaf(xa.x, wE.x, nv0); nv0 = fmaf(xa.y, wE.y, nv0);
    nv0 = fmaf(xa.z, wE.z, nv0); nv0 = fmaf(xa.w, wE.w, nv0);
    nv1 = fmaf(xb.x, wE.x, nv1); nv1 = fmaf(xb.y, wE.y, nv1);
    nv1 = fmaf(xb.z, wE.z, nv1); nv1 = fmaf(xb.w, wE.w, nv1);
    nv0 = fmaf(rdlane(acc0, 4 * ib + 0), wA.x, nv0);
    nv0 = fmaf(rdlane(acc0, 4 * ib + 1), wA.y, nv0);
    nv0 = fmaf(rdlane(acc0, 4 * ib + 2), wA.z, nv0);
    nv0 = fmaf(rdlane(acc0, 4 * ib + 3), wA.w, nv0);
    nv1 = fmaf(rdlane(acc1, 4 * ib + 0), wA.x, nv1);
    nv1 = fmaf(rdlane(acc1, 4 * ib + 1), wA.y, nv1);
    nv1 = fmaf(rdlane(acc1, 4 * ib + 2), wA.z, nv1);
    nv1 = fmaf(rdlane(acc1, 4 * ib + 3), wA.w, nv1);
  }

  // --- ctx = [self | nv0 | nv1] @ w1 + b1 ---
  float ctx = b1[lane];
  const float* w1row = &Lw1T[lane * 196];
  const float* selfp = vbase + 32 * 64;
#pragma unroll
  for (int ib = 0; ib < 16; ++ib) {
    const float4 wS = *(const float4*)&w1row[4 * ib];
    const float4 wN0 = *(const float4*)&w1row[64 + 4 * ib];
    const float4 wN1 = *(const float4*)&w1row[128 + 4 * ib];
    const float4 xs = *(const float4*)(selfp + 4 * ib);
    ctx = fmaf(xs.x, wS.x, ctx); ctx = fmaf(xs.y, wS.y, ctx);
    ctx = fmaf(xs.z, wS.z, ctx); ctx = fmaf(xs.w, wS.w, ctx);
    ctx = fmaf(rdlane(nv0, 4 * ib + 0), wN0.x, ctx);
    ctx = fmaf(rdlane(nv0, 4 * ib + 1), wN0.y, ctx);
    ctx = fmaf(rdlane(nv0, 4 * ib + 2), wN0.z, ctx);
    ctx = fmaf(rdlane(nv0, 4 * ib + 3), wN0.w, ctx);
    ctx = fmaf(rdlane(nv1, 4 * ib + 0), wN1.x, ctx);
    ctx = fmaf(rdlane(nv1, 4 * ib + 1), wN1.y, ctx);
    ctx = fmaf(rdlane(nv1, 4 * ib + 2), wN1.z, ctx);
    ctx = fmaf(rdlane(nv1, 4 * ib + 3), wN1.w, ctx);
  }

  // --- q = u @ wq + bq ---
  float q = bq[lane];
  const float* qrow = &LqT[lane * 68];
#pragma unroll
  for (int ib = 0; ib < 16; ++ib) {
    const float4 wQ = *(const float4*)&qrow[4 * ib];
    const float4 xu = *(const float4*)(user_emb + (size_t)uid * 64 + 4 * ib);
    q = fmaf(xu.x, wQ.x, q); q = fmaf(xu.y, wQ.y, q);
    q = fmaf(xu.z, wQ.z, q); q = fmaf(xu.w, wQ.w, q);
  }

  // --- K/V for 10 candidates ---
  float kk[10], vv[10];
  const float bkv = bk[lane], bvv = bv[lane];
#pragma unroll
  for (int k = 0; k < 10; ++k) { kk[k] = bkv; vv[k] = bvv; }
  const float* krow = &LkT[lane * 68];
  const float* vrow = &LvT[lane * 68];
#pragma unroll
  for (int ib = 0; ib < 16; ++ib) {
    const float4 wK = *(const float4*)&krow[4 * ib];
    const float4 wV = *(const float4*)&vrow[4 * ib];
#pragma unroll
    for (int k = 0; k < 10; ++k) {
      const float4 xt = *(const float4*)(ent_emb + (size_t)tkid[k] * 64 + 4 * ib);
      kk[k] = fmaf(xt.x, wK.x, kk[k]); kk[k] = fmaf(xt.y, wK.y, kk[k]);
      kk[k] = fmaf(xt.z, wK.z, kk[k]); kk[k] = fmaf(xt.w, wK.w, kk[k]);
      vv[k] = fmaf(xt.x, wV.x, vv[k]); vv[k] = fmaf(xt.y, wV.y, vv[k]);
      vv[k] = fmaf(xt.z, wV.z, vv[k]); vv[k] = fmaf(xt.w, wV.w, vv[k]);
    }
  }

  float lg[10];
#pragma unroll
  for (int k = 0; k < 10; ++k) lg[k] = wave_sum64(q * kk[k]) * 0.125f;  // 1/sqrt(64)
  float m = lg[0];
#pragma unroll
  for (int k = 1; k < 10; ++k) m = fmaxf(m, lg[k]);
  float den = 0.f;
  float att[10];
#pragma unroll
  for (int k = 0; k < 10; ++k) { att[k] = expf(lg[k] - m); den += att[k]; }
  const float invden = 1.0f / den;
  float uatt = 0.f;
#pragma unroll
  for (int k = 0; k < 10; ++k) uatt = fmaf(att[k] * invden, vv[k], uatt);

  const float sc = wave_sum64(uatt * ctx + ctx * w_s[lane]);
  if (lane == 0) out[b] = sc + b_s[0];
}

extern "C" void kernel_launch(void* const* d_in, const int* in_sizes, int n_in,
                              void* d_out, int out_size, void* d_ws, size_t ws_size,
                              hipStream_t stream) {
  const int* relations     = (const int*)d_in[0];
  const int* entity_pairs  = (const int*)d_in[1];
  const int* train_edges   = (const int*)d_in[2];
  const int* user_ids      = (const int*)d_in[3];
  const int* top_k_ids     = (const int*)d_in[4];
  const int* entity2edges  = (const int*)d_in[5];
  const int* edge2entities = (const int*)d_in[6];
  const int* edge2relation = (const int*)d_in[7];
  const float* ent_emb  = (const float*)d_in[8];
  const float* rel_emb  = (const float*)d_in[9];
  const float* user_emb = (const float*)d_in[10];
  const float* w_ent0 = (const float*)d_in[11];
  const float* b_ent0 = (const float*)d_in[12];
  const float* w0     = (const float*)d_in[13];
  const float* b0     = (const float*)d_in[14];
  const float* w_ent1 = (const float*)d_in[15];
  const float* b_ent1 = (const float*)d_in[16];
  const float* w1     = (const float*)d_in[17];
  const float* b1     = (const float*)d_in[18];
  const float* wq  = (const float*)d_in[19];
  const float* bq  = (const float*)d_in[20];
  const float* wk  = (const float*)d_in[21];
  const float* bk  = (const float*)d_in[22];
  const float* wv  = (const float*)d_in[23];
  const float* bv  = (const float*)d_in[24];
  const float* w_s = (const float*)d_in[25];
  const float* b_s = (const float*)d_in[26];

  const int bs = in_sizes[0];
  const int n_items = bs * 33;        // 33792
  const int rows1 = 2 * n_items;      // 67584

  // ws layout: X1 fp16 [rows1*128] (17.3MB, later aliased by v1 fp32 8.65MB) |
  //            nv fp16 [n_items*128] (8.65MB) | rsel int[n_items] (135KB)
  _Float16* X1 = (_Float16*)d_ws;
  _Float16* nvb = X1 + (size_t)rows1 * 128;
  int* rselA = (int*)(nvb + (size_t)n_items * 128);
  float* v1ws = (float*)d_ws;  // aliases X1 (dead after k_gemm1)

  k_pack<<<dim3((n_items / 4 + 7) / 8), dim3(512), 0, stream>>>(
      relations, entity_pairs, train_edges, entity2edges, edge2entities,
      edge2relation, ent_emb, rel_emb, X1, rselA, n_items);

  k_gemm1<<<dim3((rows1 + 127) / 128), dim3(256), 0, stream>>>(
      X1, w_ent0, b_ent0, nvb, rows1);

  k_gemm2<<<dim3((n_items + 63) / 64), dim3(256), 0, stream>>>(
      nvb, rselA, rel_emb, w0, b0, v1ws, n_items);

  k_ctx_score<<<dim3((bs + 3) / 4), dim3(256), 34048 * sizeof(float), stream>>>(
      entity_pairs, train_edges, user_ids, top_k_ids, entity2edges,
      ent_emb, user_emb, w_ent1, b_ent1, w1, b1, wq, bq, wk, bk, wv, bv,
      w_s, b_s, v1ws, (float*)d_out, bs);
}